// Round 1
// baseline (291.197 us; speedup 1.0000x reference)
//
#include <hip/hip_runtime.h>
#include <math.h>

// SparseCoding, round 14.
// R13 (284 us) was VALU-bound: VALUBusy 45%, MfmaUtil 0, HBM 2%. The per-iter
// coef@G GEMM (1024 scalar fma + 256 readlane per thread) was ~70% of the VALU
// work, and the 128 KB K-split exchange existed only to serve it.
// R14 moves the iteration GEMM to the matrix pipe:
//  * G = Ghi + Glo (round-nearest bf16 split, ~2^-17 rel). Per-wave B-frags
//    (2 N-tiles x 8 K-steps, hi+lo) live in 128 VGPRs, loaded once from ws G.
//  * coef rows 0-7 kept stacked [hi;lo] as a 16x256 bf16 LDS tile
//    (XOR-swizzled, double-buffered 2x8KB). One mfma_f32_16x16x32_bf16 with
//    stacked A computes hi-row and lo-row products at once:
//      a4 = (C1+C2)[row r] + (C1+C2)[row r+8]   (one shfl_xor(32) + add)
//    with C1 = Astack@Ghi, C2 = Astack@Glo -> full (hi+lo)(Ghi+Glo) product.
//  * 32 MFMA + ~200 VALU/iter replaces ~1300 VALU; K-split exchange gone.
// Ownership moves to the MFMA C layout (col = lane&15, row = 4*(lane>>4)+reg;
// lanes>=32 duplicate rows 0-7 and own the lo-row A writes). xB is computed by
// the UNCHANGED R13 VALU path (bit-identical) and redistributed once via LDS.
// Loss/convergence machinery (lag-2 consume, gpart/gcnt, s_stop parity,
// post-loop round) is byte-for-byte R13; the iteration has 2 barriers
// (A-buffer visibility + s_stop) preserving R13's exact stop semantics.
#define NB     256
#define NF     128
#define FT     1024
#define NW     63
#define TORIG  256
#define MAXIT  48
#define RPB    8
#define NBLK   4
#define GRID   256           // XCD-swizzled; 4 blocks decode w==63: gram+exit

using f32x4  = __attribute__((ext_vector_type(4))) float;
using bf16x8 = __attribute__((ext_vector_type(8))) short;

// exchange layout (float4 index): k2*512 + row*64 + (cg ^ row)  [setup xB only]
__device__ __forceinline__ int xidx(int k2, int cg, int row) {
    return (k2 * 512 + row * 64 + (cg ^ row)) * 4;
}

// round-to-nearest-even fp32 -> bf16 bits (upper 16)
__device__ __forceinline__ unsigned bf16_hi(float x) {
    const unsigned u = __float_as_uint(x);
    return (u + 0x7fffu + ((u >> 16) & 1u)) >> 16;
}

__global__ __launch_bounds__(512, 2) void window_kernel(
    const float* __restrict__ spec,
    const float* __restrict__ basis,
    float* __restrict__ G,               // ws: 256x256
    const int* __restrict__ p_niter,
    const int* __restrict__ p_pad,
    const int* __restrict__ p_stride,
    double* __restrict__ sxbuf,          // [NW][NBLK]
    double* __restrict__ gpart,          // [MAXIT][NW][NBLK][2]
    unsigned int* __restrict__ gcnt,     // [MAXIT*NW] arrivals + [MAXIT*NW]=gbar
    float* __restrict__ out)             // (32,256,63)
{
    __shared__ __align__(16) float s_p0[RPB * 2048];   // 64 KB xB exchange (setup)
    __shared__ __align__(16) float s_xn[RPB * FT];     // 32 KB staging + xB scratch
    __shared__ __align__(16) short A0[16 * NB];        // 8 KB stacked bf16 coef
    __shared__ __align__(16) short A1[16 * NB];        //   (hi rows 0-7, lo 8-15)
    __shared__ float  s_gred[2][NB];
    __shared__ float  s_mn[RPB], s_rng[RPB];
    __shared__ double s_dred[8];
    __shared__ float  s_redq[2][8], s_redr[2][8];
    __shared__ unsigned int s_wcnt[2];
    __shared__ int    s_stop[2];

    const int bid = blockIdx.x;
    const int yy  = bid >> 3;
    const int q   = yy & 3;
    const int w   = (bid & 7) + 8 * (yy >> 2);   // 4 blocks/window share bid%8 (XCD)
    const int tid = threadIdx.x;
    const int ks  = tid >> 6;                    // wave index
    const int kg  = tid & 63;
    const int r   = kg >> 3;                     // setup-phase owned row
    const int cgo = 8 * ks + (kg & 7);           // setup-phase owned colgroup
    const int n_iter = p_niter[0];
    const int t0     = w * p_stride[0] - p_pad[0];
    unsigned int* gbar = gcnt + MAXIT * NW;

    // ================= fused Gram: block bid computes G row bid ==================
    {
        const int c = tid & 255, jh = tid >> 8;
        float acc = 0.f;
        const float* bp = basis + (size_t)(jh * 512) * NB;
        #pragma unroll 16
        for (int j = 0; j < 512; ++j)
            acc = fmaf(bp[j * NB + bid], bp[j * NB + c], acc);
        s_gred[jh][c] = acc;
        __syncthreads();
        if (jh == 0) G[(size_t)bid * NB + c] = s_gred[0][c] + s_gred[1][c];
    }
    __threadfence();
    __syncthreads();
    if (tid == 0) atomicAdd(gbar, 1u);
    if (w >= NW) return;

    // ================= stage raw window, min/max, normalize ======================
    #pragma unroll
    for (int i = 0; i < 16; ++i) {
        const int e = i * 512 + tid;
        const int b = e >> 10, jj = e & 1023;
        const int f = jj >> 3, t = jj & 7, tq = t0 + t;
        s_xn[b * FT + jj] = (tq >= 0 && tq < TORIG)
            ? spec[((size_t)(q * RPB + b) * NF + f) * TORIG + tq] : 0.f;
    }
    __syncthreads();
    {   // wave ks scans row ks
        float mn = __builtin_inff(), mx = -__builtin_inff();
        #pragma unroll
        for (int i = 0; i < 16; ++i) {
            const float v = s_xn[ks * FT + i * 64 + kg];
            mn = fminf(mn, v); mx = fmaxf(mx, v);
        }
        #pragma unroll
        for (int off = 32; off; off >>= 1) {
            mn = fminf(mn, __shfl_down(mn, off));
            mx = fmaxf(mx, __shfl_down(mx, off));
        }
        if (kg == 0) { s_mn[ks] = mn; s_rng[ks] = mx - mn; }
    }
    __syncthreads();
    double sx2p = 0.0;
    #pragma unroll
    for (int i = 0; i < 16; ++i) {
        const int e = i * 512 + tid;
        const int b = e >> 10, jj = e & 1023;
        const float v = (s_xn[b * FT + jj] - s_mn[b]) / s_rng[b];
        s_xn[b * FT + jj] = v;
        sx2p += (double)v * (double)v;
    }
    #pragma unroll
    for (int off = 32; off; off >>= 1) sx2p += __shfl_down(sx2p, off);
    if (kg == 0) s_dred[ks] = sx2p;
    __syncthreads();
    if (tid == 0) {
        double s = 0.0;
        #pragma unroll
        for (int i = 0; i < 8; ++i) s += s_dred[i];
        sxbuf[w * NBLK + q] = s;
        __threadfence();
    }

    // ====== xB = xnorm @ basis (R13 path, bit-identical; K-split partials) =======
    float xbp[RPB][4];
    #pragma unroll
    for (int b = 0; b < RPB; ++b)
        #pragma unroll
        for (int j = 0; j < 4; ++j) xbp[b][j] = 0.f;
    for (int i0 = 0; i0 < 128; i0 += 4) {
        const int jj = ks * 128 + i0;
        float4 bv[4];
        #pragma unroll
        for (int t = 0; t < 4; ++t)
            bv[t] = *(const float4*)(basis + (size_t)(jj + t) * NB + 4 * kg);
        #pragma unroll
        for (int b = 0; b < RPB; ++b) {
            const float4 x4 = *(const float4*)&s_xn[b * FT + jj];
            xbp[b][0] = fmaf(x4.x, bv[0].x, fmaf(x4.y, bv[1].x, fmaf(x4.z, bv[2].x, fmaf(x4.w, bv[3].x, xbp[b][0]))));
            xbp[b][1] = fmaf(x4.x, bv[0].y, fmaf(x4.y, bv[1].y, fmaf(x4.z, bv[2].y, fmaf(x4.w, bv[3].y, xbp[b][1]))));
            xbp[b][2] = fmaf(x4.x, bv[0].z, fmaf(x4.y, bv[1].z, fmaf(x4.z, bv[2].z, fmaf(x4.w, bv[3].z, xbp[b][2]))));
            xbp[b][3] = fmaf(x4.x, bv[0].w, fmaf(x4.y, bv[1].w, fmaf(x4.z, bv[2].w, fmaf(x4.w, bv[3].w, xbp[b][3]))));
        }
    }
    __syncthreads();
    #pragma unroll
    for (int b = 0; b < RPB; ++b)
        *(float4*)&s_p0[xidx(ks, kg, b)] =
            make_float4(xbp[b][0], xbp[b][1], xbp[b][2], xbp[b][3]);
    __syncthreads();
    float xBo[4] = {0.f, 0.f, 0.f, 0.f};
    #pragma unroll
    for (int k2 = 0; k2 < 8; ++k2) {
        const float4 p4 = *(const float4*)&s_p0[xidx(k2, cgo, r)];
        xBo[0] += p4.x; xBo[1] += p4.y; xBo[2] += p4.z; xBo[3] += p4.w;
    }
    // redistribute xB to the MFMA C layout via s_xn scratch (staging is dead)
    *(float4*)&s_xn[r * NB + 4 * cgo] = make_float4(xBo[0], xBo[1], xBo[2], xBo[3]);

    // ================= wait for G; init block-local sync =========================
    if (tid == 0) {
        while (__hip_atomic_load(gbar, __ATOMIC_ACQUIRE, __HIP_MEMORY_SCOPE_AGENT) < (unsigned)GRID)
            __builtin_amdgcn_s_sleep(1);
    }
    if (tid == 64) { s_wcnt[0] = 0; s_wcnt[1] = 0; s_stop[0] = 0; s_stop[1] = 0; }
    __syncthreads();

    // ============== MFMA-layout ownership & fragment constants ===================
    const int lr  = kg & 15;        // C col within tile
    const int lh  = kg >> 4;        // lane group 0..3
    const int hlf = kg >> 5;        // 0 = hi rows, 1 = lo rows (duplicate owner)

    float xB[8];
    #pragma unroll
    for (int T = 0; T < 2; ++T)
        #pragma unroll
        for (int t = 0; t < 4; ++t)
            xB[4*T + t] = s_xn[(4*(lh & 1) + t) * NB + 32*ks + 16*T + lr];

    // G B-fragments, hi/lo bf16 split. B layout: col = lane&15, k = 8*(lane>>4)+b.
    bf16x8 Gh[8][2], Gl[8][2];
    {
        const float* gp = G + (size_t)(8 * lh) * NB + 32 * ks + lr;
        #pragma unroll
        for (int kk = 0; kk < 8; ++kk)
            #pragma unroll
            for (int T = 0; T < 2; ++T)
                #pragma unroll
                for (int b = 0; b < 8; ++b) {
                    const float gv = gp[(size_t)(32*kk + b) * NB + 16*T];
                    const unsigned hb = bf16_hi(gv);
                    const float    hf = __uint_as_float(hb << 16);
                    const unsigned lb = bf16_hi(gv - hf);
                    Gh[kk][T][b] = (short)hb;
                    Gl[kk][T][b] = (short)lb;
                }
    }

    // A-tile addressing. A layout: row = lane&15, k = 8*(lane>>4)+b.
    // Swizzle: short-idx ^= (row&7)<<3  (16B granule spread across banks).
    unsigned awaddr[8];
    #pragma unroll
    for (int T = 0; T < 2; ++T)
        #pragma unroll
        for (int t = 0; t < 4; ++t) {
            const int hr  = 4*(lh & 1) + t;
            const int col = 32*ks + 16*T + lr;
            awaddr[4*T + t] = (unsigned)((((hr * NB + col) ^ ((hr & 7) << 3)) * 2)
                                         + (hlf ? 4096 : 0));
        }
    const unsigned abase = (unsigned)(((lr * NB + lh * 8) ^ ((lr & 7) << 3)) * 2);

    // ================= init owned coef / Adam; write A0 ==========================
    const float C0 = 0.5f / 256.f;
    float cf[8], cfp[8], m_[8], v_[8];
    #pragma unroll
    for (int j = 0; j < 8; ++j) { cf[j] = C0; cfp[j] = C0; m_[j] = 0.f; v_[j] = 0.f; }
    {
        const short vh  = (short)bf16_hi(C0);     // C0 = 2^-9: exact, lo = 0
        const short val = hlf ? (short)0 : vh;
        #pragma unroll
        for (int j = 0; j < 8; ++j)
            *(short*)((char*)A0 + awaddr[j]) = val;
    }
    float b1p = 1.f, b2p = 1.f;
    float old_loss = 1e-10f;      // tid64 only
    double sxtot = 0.0;           // tid64 only
    const float c1c = 2.f / 32768.f, c2c = 0.2f / 8192.f;
    int use_prev = 0;

    for (int it = 0; it < n_iter; ++it) {
        const int p = it & 1;
        const char* rdb = (const char*)(p ? A1 : A0);
        char*       wrb = (char*)(p ? A0 : A1);

        __syncthreads();          // barrier 1: A[rd] writes (prev iter) visible

        // ---- MFMA: Astack(16x256) @ G, wave ks owns cols 32ks..32ks+32 ----
        f32x4 a1[2], a2[2];
        const f32x4 z4 = {0.f, 0.f, 0.f, 0.f};
        a1[0] = z4; a1[1] = z4; a2[0] = z4; a2[1] = z4;
        #pragma unroll
        for (int kk = 0; kk < 8; ++kk) {
            const bf16x8 af = *(const bf16x8*)(rdb + (abase ^ (unsigned)(kk << 6)));
            a1[0] = __builtin_amdgcn_mfma_f32_16x16x32_bf16(af, Gh[kk][0], a1[0], 0, 0, 0);
            a2[0] = __builtin_amdgcn_mfma_f32_16x16x32_bf16(af, Gl[kk][0], a2[0], 0, 0, 0);
            a1[1] = __builtin_amdgcn_mfma_f32_16x16x32_bf16(af, Gh[kk][1], a1[1], 0, 0, 0);
            a2[1] = __builtin_amdgcn_mfma_f32_16x16x32_bf16(af, Gl[kk][1], a2[1], 0, 0, 0);
        }
        float a4[8];
        #pragma unroll
        for (int T = 0; T < 2; ++T)
            #pragma unroll
            for (int t = 0; t < 4; ++t) {
                const float s = a1[T][t] + a2[T][t];
                a4[4*T + t] = s + __shfl_xor(s, 32);   // hi-row + lo-row halves
            }

        // ---- tid64: LAG-2 consume (R13, unchanged) ----
        if (tid == 64 && it >= 2) {
            const int itc = it - 2;
            while (__hip_atomic_load(&gcnt[itc * NW + w], __ATOMIC_ACQUIRE,
                                     __HIP_MEMORY_SCOPE_AGENT) < (unsigned)NBLK)
                __builtin_amdgcn_s_sleep(1);
            const size_t pbm = ((size_t)itc * NW + w) * NBLK;
            double Qt = 0.0, Rt = 0.0;
            #pragma unroll
            for (int i = 0; i < NBLK; ++i) {
                Qt += gpart[(pbm + i) * 2 + 0];
                Rt += gpart[(pbm + i) * 2 + 1];
            }
            if (itc == 0)
                sxtot = sxbuf[w * NBLK + 0] + sxbuf[w * NBLK + 1] +
                        sxbuf[w * NBLK + 2] + sxbuf[w * NBLK + 3];
            const float loss = (float)((Qt + sxtot) / 32768.0 + 0.2 * (Rt / 8192.0));
            const float stat = fabsf(old_loss - loss) / old_loss;
            old_loss = loss;
            s_stop[p] = (stat < 1e-3f) ? 1 : 0;
        }

        __syncthreads();          // barrier 2: s_stop[p] visible

        if (s_stop[p]) { use_prev = 1; break; }   // t*=it-2 -> answer = cfp

        // ---- loss partials + last-man-out block post (skip on final iter) ----
        if (it + 1 < n_iter) {
            float qc = 0.f, rr = 0.f;
            #pragma unroll
            for (int j = 0; j < 8; ++j) {
                qc += cf[j] * (a4[j] - 2.f * xB[j]);
                rr += fabsf(cf[j]);
            }
            if (kg >= 32) { qc = 0.f; rr = 0.f; }   // upper half duplicates
            #pragma unroll
            for (int off = 32; off; off >>= 1) {
                qc += __shfl_down(qc, off);
                rr += __shfl_down(rr, off);
            }
            if (kg == 0) {
                s_redq[p][ks] = qc; s_redr[p][ks] = rr;
                __threadfence_block();
                const unsigned old = __hip_atomic_fetch_add(&s_wcnt[p], 1u,
                                        __ATOMIC_ACQ_REL, __HIP_MEMORY_SCOPE_WORKGROUP);
                if (old == 7u) {
                    float Q = 0.f, R = 0.f;
                    #pragma unroll
                    for (int i = 0; i < 8; ++i) { Q += s_redq[p][i]; R += s_redr[p][i]; }
                    s_wcnt[p] = 0u;
                    const size_t pb = ((size_t)it * NW + w) * NBLK;
                    gpart[(pb + q) * 2 + 0] = (double)Q;
                    gpart[(pb + q) * 2 + 1] = (double)R;
                    __hip_atomic_fetch_add(&gcnt[it * NW + w], 1u,
                                           __ATOMIC_RELEASE, __HIP_MEMORY_SCOPE_AGENT);
                }
            }
        }

        // ---- Adam update (fast rcp/sqrt; cfp snapshot first) ----
        b1p *= 0.9f; b2p *= 0.999f;
        const float rb1 = __builtin_amdgcn_rcpf(1.f - b1p);
        const float rb2 = __builtin_amdgcn_rcpf(1.f - b2p);
        #pragma unroll
        for (int j = 0; j < 8; ++j) {
            const float c_ = cf[j];
            cfp[j] = c_;
            const float sgn = (c_ > 0.f) ? 1.f : ((c_ < 0.f) ? -1.f : 0.f);
            const float gg = c1c * (a4[j] - xB[j]) + c2c * sgn;
            m_[j] = 0.9f * m_[j] + 0.1f * gg;
            v_[j] = 0.999f * v_[j] + 0.001f * gg * gg;
            const float den = __builtin_amdgcn_sqrtf(v_[j] * rb2) + 1e-8f;
            cf[j] = c_ - 1e-3f * (m_[j] * rb1) * __builtin_amdgcn_rcpf(den);
        }

        // ---- bf16 hi/lo split of new coef -> next A buffer ----
        #pragma unroll
        for (int j = 0; j < 8; ++j) {
            const unsigned hb = bf16_hi(cf[j]);
            const float    hf = __uint_as_float(hb << 16);
            const unsigned lb = bf16_hi(cf[j] - hf);
            *(short*)(wrb + awaddr[j]) = (short)(hlf ? lb : hb);
        }
    }

    // ---- post-loop consume round: conv at t = n_iter-2 (if not already stopped) ----
    if (!use_prev && n_iter >= 2) {
        if (tid == 64) {
            const int itc = n_iter - 2;
            while (__hip_atomic_load(&gcnt[itc * NW + w], __ATOMIC_ACQUIRE,
                                     __HIP_MEMORY_SCOPE_AGENT) < (unsigned)NBLK)
                __builtin_amdgcn_s_sleep(1);
            const size_t pbm = ((size_t)itc * NW + w) * NBLK;
            double Qt = 0.0, Rt = 0.0;
            #pragma unroll
            for (int i = 0; i < NBLK; ++i) {
                Qt += gpart[(pbm + i) * 2 + 0];
                Rt += gpart[(pbm + i) * 2 + 1];
            }
            if (itc == 0)
                sxtot = sxbuf[w * NBLK + 0] + sxbuf[w * NBLK + 1] +
                        sxbuf[w * NBLK + 2] + sxbuf[w * NBLK + 3];
            const float loss = (float)((Qt + sxtot) / 32768.0 + 0.2 * (Rt / 8192.0));
            const float stat = fabsf(old_loss - loss) / old_loss;
            s_stop[0] = (stat < 1e-3f) ? 1 : 0;
        }
        __syncthreads();
        use_prev = s_stop[0];
    }

    // ---- out[b][k][w]: lanes<32 own rows 0-7 (upper half duplicates) ----
    if (kg < 32) {
        #pragma unroll
        for (int T = 0; T < 2; ++T)
            #pragma unroll
            for (int t = 0; t < 4; ++t)
                out[((size_t)(q * RPB + 4*lh + t) * NB + 32*ks + 16*T + lr) * NW + w] =
                    use_prev ? cfp[4*T + t] : cf[4*T + t];
    }
}

// ---------------------------------------------------------------------------
extern "C" void kernel_launch(void* const* d_in, const int* in_sizes, int n_in,
                              void* d_out, int out_size, void* d_ws, size_t ws_size,
                              hipStream_t stream)
{
    const float* spec   = (const float*)d_in[0];
    const float* basis  = (const float*)d_in[1];
    const int* p_niter  = (const int*)d_in[2];
    const int* p_pad    = (const int*)d_in[3];
    const int* p_stride = (const int*)d_in[4];
    float* out = (float*)d_out;

    char* ws = (char*)d_ws;
    float*        G     = (float*)ws;                         // 256 KB
    double*       sxbuf = (double*)(ws + 262144);             // 2016 B (pad 4 KB)
    double*       gpart = (double*)(ws + 266240);             // 193536 B
    unsigned int* gcnt  = (unsigned int*)(ws + 266240 + 193536); // (MAXIT*NW+1)*4

    hipMemsetAsync(gcnt, 0, (MAXIT * NW + 1) * sizeof(unsigned int), stream);
    window_kernel<<<dim3(GRID), dim3(512), 0, stream>>>(
        spec, basis, G, p_niter, p_pad, p_stride, sxbuf, gpart, gcnt, out);
}